// Round 8
// baseline (176.361 us; speedup 1.0000x reference)
//
#include <hip/hip_runtime.h>
#include <stdint.h>

#define N_NODES 100000
#define N_EDGES 1600000
#define HIDDEN  64
#define SLOPE   0.01f
#define NBUCK   782      // ceil(N_NODES/128): coarse buckets of 128 dst nodes
#define CAPB    2816     // fixed slots per bucket (mean 2048, sd 45 -> 17 sigma)
#define PCHUNK  4096     // edges per partition chunk
#define NPART   391      // ceil(N_EDGES/PCHUNK)
#define NSB     25000    // scores blocks (4 nodes each)
#define CAP     1024     // LDS staging cap per 32-node sub-bucket (mean 512, sd 23)

// round-to-nearest-even fp32 -> bf16 (as ushort)
__device__ __forceinline__ unsigned short f2bf(float f) {
    uint32_t u = __float_as_uint(f);
    uint32_t r = u + 0x7FFFu + ((u >> 16) & 1u);
    return (unsigned short)(r >> 16);
}

// K1: fused build. Blocks [0, NSB): per-node scores + bf16 x copy.
//     Blocks [NSB, NSB+NPART): partition one 4096-edge chunk into
//     fixed-capacity bucket slabs (R7 ran partition at 1.5 blocks/CU —
//     starved; the mixed grid saturates the device with both workloads).
__global__ void __launch_bounds__(256) k_build(const float* __restrict__ x,
                                               const float* __restrict__ w_i,
                                               const float* __restrict__ w_j,
                                               const int* __restrict__ srcs,
                                               const int* __restrict__ dsts,
                                               float* __restrict__ s_i,
                                               float* __restrict__ s_j,
                                               unsigned short* __restrict__ xb,
                                               int* __restrict__ cursor,
                                               uint32_t* __restrict__ pairs) {
    __shared__ int lcnt[NBUCK], lbase[NBUCK];
    int tid = threadIdx.x;
    if (blockIdx.x < NSB) {
        int node = blockIdx.x * 4 + (tid >> 6);
        int lane = tid & 63;
        if (node >= N_NODES) return;
        float v = x[node * HIDDEN + lane];
        xb[node * HIDDEN + lane] = f2bf(v);
        float a = v * w_i[lane];
        float b = v * w_j[lane];
        for (int off = 32; off > 0; off >>= 1) {
            a += __shfl_xor(a, off, 64);
            b += __shfl_xor(b, off, 64);
        }
        if (lane == 0) { s_i[node] = a; s_j[node] = b; }
        return;
    }
    // ---- partition part (block-uniform branch; syncthreads are safe) ----
    int pb = blockIdx.x - NSB;
    for (int b = tid; b < NBUCK; b += 256) lcnt[b] = 0;
    __syncthreads();
    int e0 = pb * PCHUNK;
    int e1 = min(e0 + PCHUNK, N_EDGES);
    for (int e = e0 + tid; e < e1; e += 256)
        atomicAdd(&lcnt[dsts[e] >> 7], 1);
    __syncthreads();
    for (int b = tid; b < NBUCK; b += 256) {
        int c = lcnt[b];
        lbase[b] = c ? atomicAdd(&cursor[b], c) : 0;
        lcnt[b] = 0;                      // reuse as rank counter
    }
    __syncthreads();
    for (int e = e0 + tid; e < e1; e += 256) {
        int src = srcs[e];
        int dst = dsts[e];
        int b = dst >> 7;
        int r = atomicAdd(&lcnt[b], 1);
        int pos = lbase[b] + r;
        if (pos < CAPB)                   // 17-sigma guard, never taken
            pairs[(size_t)b * CAPB + pos] =
                ((uint32_t)(dst & 127) << 24) | (uint32_t)src;
    }
}

// bf16-pair unpack helpers
__device__ __forceinline__ float bflo(uint32_t d) { return __uint_as_float(d << 16); }
__device__ __forceinline__ float bfhi(uint32_t d) { return __uint_as_float(d & 0xFFFF0000u); }

// batch of L load instructions covering 4L edges: quarter-wave q handles
// edges i+4t+q; lane (q, ql) loads uint2 = dims {4ql..4ql+3} of its edge's
// row (16 lanes x 8 B = one full 128 B row per edge).
template <int L>
__device__ __forceinline__ void gat_batch4(const uint64_t* pp, int i, int quarter, int ql,
                                           const uint2* __restrict__ xw2,
                                           float acc[4], float& den) {
    uint64_t q[L];
    uint2 d[L];
#pragma unroll
    for (int t = 0; t < L; ++t) q[t] = pp[i + 4 * t + quarter];
#pragma unroll
    for (int t = 0; t < L; ++t)
        d[t] = xw2[((uint32_t)q[t] & 0xFFFFFFu) * 16 + ql];
#pragma unroll
    for (int t = 0; t < L; ++t) {
        float w = __uint_as_float((uint32_t)(q[t] >> 32));
        den += w;
        acc[0] = fmaf(w, bflo(d[t].x), acc[0]);
        acc[1] = fmaf(w, bfhi(d[t].x), acc[1]);
        acc[2] = fmaf(w, bflo(d[t].y), acc[2]);
        acc[3] = fmaf(w, bfhi(d[t].y), acc[3]);
    }
}

// K2: one block per 32 nodes. Stage {w,src} per node into LDS, then
//     quarter-wave gathers: one load instruction covers 4 edges, so an
//     average node (c~16) needs ONE memory wait and ~2.5x fewer VALU
//     instructions than the R7 half-wave version.
__global__ void __launch_bounds__(256, 8) k_bucket_agg(const uint2* __restrict__ xw2,
                                                       const uint32_t* __restrict__ pairs,
                                                       const int* __restrict__ cursor,
                                                       const float* __restrict__ s_i,
                                                       const float* __restrict__ s_j,
                                                       float* __restrict__ out) {
    __shared__ uint64_t spairs[CAP];
    __shared__ int scnt[32], soff[32], scnt2[32];
    __shared__ float s_si[32];
    __shared__ int sovf;
    int tid = threadIdx.x;
    int g = blockIdx.x;                   // 32 nodes per block
    int cb = g >> 2, sub = g & 3;
    int node0 = g * 32;
    const uint32_t* reg = pairs + (size_t)cb * CAPB;
    int rcnt = min(cursor[cb], CAPB);
    if (tid < 32) {
        scnt[tid] = 0; scnt2[tid] = 0;
        int node = node0 + tid;
        s_si[tid] = (node < N_NODES) ? s_i[node] : 0.f;
    }
    if (tid == 0) sovf = 0;
    __syncthreads();
    // pass A: per-node degree count for this 32-node sub-bucket
    for (int e = tid; e < rcnt; e += 256) {
        int dstl = (int)(reg[e] >> 24);
        if ((dstl >> 5) == sub) atomicAdd(&scnt[dstl & 31], 1);
    }
    __syncthreads();
    // exclusive scan of 32 counts (first wave, shfl)
    if (tid < 32) {
        int v = scnt[tid], s = v;
        for (int o = 1; o < 32; o <<= 1) {
            int t = __shfl_up(s, o, 64);
            if (tid >= o) s += t;
        }
        soff[tid] = s - v;
        if (tid == 31 && s > CAP) sovf = 1;
    }
    __syncthreads();
    int ovf = sovf;
    if (!ovf) {
        // pass B: w = exp(leaky(s_i+s_j)); scatter {w,src} per node into LDS
        for (int e = tid; e < rcnt; e += 256) {
            uint32_t p = reg[e];
            int dstl = (int)(p >> 24);
            if ((dstl >> 5) == sub) {
                int n = dstl & 31;
                int src = (int)(p & 0xFFFFFFu);
                float sc = s_si[n] + s_j[src];
                sc = (sc > 0.f) ? sc : SLOPE * sc;
                float w = __expf(sc);
                int r = atomicAdd(&scnt2[n], 1);
                spairs[soff[n] + r] =
                    ((uint64_t)__float_as_uint(w) << 32) | (uint32_t)src;
            }
        }
    }
    __syncthreads();
    int wave = tid >> 6, lane = tid & 63;
    int quarter = lane >> 4, ql = lane & 15;
    for (int k = wave; k < 32; k += 4) {
        int node = node0 + k;
        if (node >= N_NODES) break;
        float acc[4] = {0.f, 0.f, 0.f, 0.f};
        float den = 0.f;
        int c = scnt[k];
        if (!ovf) {
            const uint64_t* pp = spairs + soff[k];
            int i = 0;
            for (; i + 16 <= c; i += 16) gat_batch4<4>(pp, i, quarter, ql, xw2, acc, den);
            if (i + 8 <= c) { gat_batch4<2>(pp, i, quarter, ql, xw2, acc, den); i += 8; }
            if (i + 4 <= c) { gat_batch4<1>(pp, i, quarter, ql, xw2, acc, den); i += 4; }
            int rem = c - i;
            if (rem > 0) {
                // masked final batch: inactive quarters load a valid row, w=0
                uint64_t q = pp[i + min(quarter, rem - 1)];
                float w = (quarter < rem) ? __uint_as_float((uint32_t)(q >> 32)) : 0.f;
                uint2 d = xw2[((uint32_t)q & 0xFFFFFFu) * 16 + ql];
                den += w;
                acc[0] = fmaf(w, bflo(d.x), acc[0]);
                acc[1] = fmaf(w, bfhi(d.x), acc[1]);
                acc[2] = fmaf(w, bflo(d.y), acc[2]);
                acc[3] = fmaf(w, bfhi(d.y), acc[3]);
            }
        } else {
            // safe fallback (statistically unreachable): scan whole region;
            // only quarter 0 applies weight, other quarters contribute 0
            int sn = (sub << 5) | k;
            for (int e = 0; e < rcnt; ++e) {
                uint32_t p = reg[e];
                if ((int)(p >> 24) == sn) {
                    int src = (int)(p & 0xFFFFFFu);
                    float sc = s_si[k] + s_j[src];
                    sc = (sc > 0.f) ? sc : SLOPE * sc;
                    float w = (quarter == 0) ? __expf(sc) : 0.f;
                    uint2 d = xw2[(uint32_t)src * 16 + ql];
                    den += w;
                    acc[0] = fmaf(w, bflo(d.x), acc[0]);
                    acc[1] = fmaf(w, bfhi(d.x), acc[1]);
                    acc[2] = fmaf(w, bflo(d.y), acc[2]);
                    acc[3] = fmaf(w, bfhi(d.y), acc[3]);
                }
            }
        }
        // combine the 4 quarters; lanes 0-15 then hold dims {4ql..4ql+3}
#pragma unroll
        for (int j = 0; j < 4; ++j) {
            acc[j] += __shfl_xor(acc[j], 16, 64);
            acc[j] += __shfl_xor(acc[j], 32, 64);
        }
        den += __shfl_xor(den, 16, 64);
        den += __shfl_xor(den, 32, 64);
        if (quarter == 0) {
            float4 r = make_float4(0.f, 0.f, 0.f, 0.f);
            if (c > 0) {
                float inv = 1.f / den;
                r.x = fmaxf(acc[0] * inv, 0.f);
                r.y = fmaxf(acc[1] * inv, 0.f);
                r.z = fmaxf(acc[2] * inv, 0.f);
                r.w = fmaxf(acc[3] * inv, 0.f);
            }
            ((float4*)(out + (size_t)node * HIDDEN))[ql] = r;
        }
    }
}

extern "C" void kernel_launch(void* const* d_in, const int* in_sizes, int n_in,
                              void* d_out, int out_size, void* d_ws, size_t ws_size,
                              hipStream_t stream) {
    const float* x   = (const float*)d_in[0];
    const int*   ei  = (const int*)d_in[1];   // [2, E]: row0 = src (ej), row1 = dst (ei)
    const float* w_i = (const float*)d_in[2];
    const float* w_j = (const float*)d_in[3];
    float* out = (float*)d_out;

    char* p = (char*)d_ws;
    float*          s_i    = (float*)p;          p += (size_t)N_NODES * 4;
    float*          s_j    = (float*)p;          p += (size_t)N_NODES * 4;
    unsigned short* xb     = (unsigned short*)p; p += (size_t)N_NODES * HIDDEN * 2;
    int*            cursor = (int*)p;            p += 4096;
    uint32_t*       pairs  = (uint32_t*)p;       // NBUCK * CAPB * 4 B = 8.8 MB

    const int* srcs = ei;             // edge_index[0]
    const int* dsts = ei + N_EDGES;   // edge_index[1]

    hipMemsetAsync(cursor, 0, NBUCK * sizeof(int), stream);
    k_build     <<<NSB + NPART, 256, 0, stream>>>(x, w_i, w_j, srcs, dsts,
                                                  s_i, s_j, xb, cursor, pairs);
    k_bucket_agg<<<(N_NODES + 31) / 32, 256, 0, stream>>>((const uint2*)xb, pairs, cursor,
                                                          s_i, s_j, out);
}

// Round 9
// 159.946 us; speedup vs baseline: 1.1026x; 1.1026x over previous
//
#include <hip/hip_runtime.h>
#include <stdint.h>

#define N_NODES 100000
#define N_EDGES 1600000
#define HIDDEN  64
#define SLOPE   0.01f
#define NBUCK   782      // ceil(N_NODES/128): coarse buckets of 128 dst nodes
#define CAPB    2816     // fixed slots per bucket (mean 2048, sd 45 -> 17 sigma)
#define PCHUNK  4096     // edges per partition chunk
#define NPART   391      // ceil(N_EDGES/PCHUNK)
#define NSB     25000    // scores blocks (4 nodes each)
#define NCAP    48       // LDS slots per node (deg ~ Poisson(16); P(>48) ~ 3e-10)

// round-to-nearest-even fp32 -> bf16 (as ushort)
__device__ __forceinline__ unsigned short f2bf(float f) {
    uint32_t u = __float_as_uint(f);
    uint32_t r = u + 0x7FFFu + ((u >> 16) & 1u);
    return (unsigned short)(r >> 16);
}

// K1: fused build. Blocks [0, NPART): partition one 4096-edge chunk into
//     fixed-capacity bucket slabs — placed FIRST in the grid so they start
//     at t=0 and overlap the scores blocks (R8 had them last: starved tail
//     at 1.5 blocks/CU after the grid drained). Blocks [NPART, NPART+NSB):
//     per-node scores + bf16 x copy.
__global__ void __launch_bounds__(256) k_build(const float* __restrict__ x,
                                               const float* __restrict__ w_i,
                                               const float* __restrict__ w_j,
                                               const int* __restrict__ srcs,
                                               const int* __restrict__ dsts,
                                               float* __restrict__ s_i,
                                               float* __restrict__ s_j,
                                               unsigned short* __restrict__ xb,
                                               int* __restrict__ cursor,
                                               uint32_t* __restrict__ pairs) {
    __shared__ int lcnt[NBUCK], lbase[NBUCK];
    int tid = threadIdx.x;
    if (blockIdx.x >= NPART) {
        int node = (blockIdx.x - NPART) * 4 + (tid >> 6);
        int lane = tid & 63;
        if (node >= N_NODES) return;
        float v = x[node * HIDDEN + lane];
        xb[node * HIDDEN + lane] = f2bf(v);
        float a = v * w_i[lane];
        float b = v * w_j[lane];
        for (int off = 32; off > 0; off >>= 1) {
            a += __shfl_xor(a, off, 64);
            b += __shfl_xor(b, off, 64);
        }
        if (lane == 0) { s_i[node] = a; s_j[node] = b; }
        return;
    }
    // ---- partition part (block-uniform branch; syncthreads are safe) ----
    for (int b = tid; b < NBUCK; b += 256) lcnt[b] = 0;
    __syncthreads();
    int e0 = blockIdx.x * PCHUNK;
    int e1 = min(e0 + PCHUNK, N_EDGES);
    for (int e = e0 + tid; e < e1; e += 256)
        atomicAdd(&lcnt[dsts[e] >> 7], 1);
    __syncthreads();
    for (int b = tid; b < NBUCK; b += 256) {
        int c = lcnt[b];
        lbase[b] = c ? atomicAdd(&cursor[b], c) : 0;
        lcnt[b] = 0;                      // reuse as rank counter
    }
    __syncthreads();
    for (int e = e0 + tid; e < e1; e += 256) {
        int src = srcs[e];
        int dst = dsts[e];
        int b = dst >> 7;
        int r = atomicAdd(&lcnt[b], 1);
        int pos = lbase[b] + r;
        if (pos < CAPB)                   // 17-sigma guard, never taken
            pairs[(size_t)b * CAPB + pos] =
                ((uint32_t)(dst & 127) << 24) | (uint32_t)src;
    }
}

// bf16-pair unpack helpers
__device__ __forceinline__ float bflo(uint32_t d) { return __uint_as_float(d << 16); }
__device__ __forceinline__ float bfhi(uint32_t d) { return __uint_as_float(d & 0xFFFF0000u); }

// batch of L load instructions covering 4L edges: quarter-wave q handles
// edges i+4t+q; lane (q, ql) loads uint2 = dims {4ql..4ql+3} of its edge's
// row (16 lanes x 8 B = one full 128 B row per edge).
template <int L>
__device__ __forceinline__ void gat_batch4(const uint64_t* pp, int i, int quarter, int ql,
                                           const uint2* __restrict__ xw2,
                                           float acc[4], float& den) {
    uint64_t q[L];
    uint2 d[L];
#pragma unroll
    for (int t = 0; t < L; ++t) q[t] = pp[i + 4 * t + quarter];
#pragma unroll
    for (int t = 0; t < L; ++t)
        d[t] = xw2[((uint32_t)q[t] & 0xFFFFFFu) * 16 + ql];
#pragma unroll
    for (int t = 0; t < L; ++t) {
        float w = __uint_as_float((uint32_t)(q[t] >> 32));
        den += w;
        acc[0] = fmaf(w, bflo(d[t].x), acc[0]);
        acc[1] = fmaf(w, bfhi(d[t].x), acc[1]);
        acc[2] = fmaf(w, bflo(d[t].y), acc[2]);
        acc[3] = fmaf(w, bfhi(d[t].y), acc[3]);
    }
}

// K2: one block per 32 nodes. SINGLE staging pass (R8 scanned the region
//     twice: count+scan, then scatter): fixed NCAP slots per node, direct
//     scatter via per-node LDS cursors; per-node fallback to a region scan
//     on (statistically negligible) overflow. Then quarter-wave gathers.
__global__ void __launch_bounds__(256, 8) k_bucket_agg(const uint2* __restrict__ xw2,
                                                       const uint32_t* __restrict__ pairs,
                                                       const int* __restrict__ cursor,
                                                       const float* __restrict__ s_i,
                                                       const float* __restrict__ s_j,
                                                       float* __restrict__ out) {
    __shared__ uint64_t spairs[32 * NCAP];   // 12.3 KB
    __shared__ int lcur[32];
    __shared__ float s_si[32];
    int tid = threadIdx.x;
    int g = blockIdx.x;                   // 32 nodes per block
    int cb = g >> 2, sub = g & 3;
    int node0 = g * 32;
    const uint32_t* reg = pairs + (size_t)cb * CAPB;
    int rcnt = min(cursor[cb], CAPB);
    if (tid < 32) {
        lcur[tid] = 0;
        int node = node0 + tid;
        s_si[tid] = (node < N_NODES) ? s_i[node] : 0.f;
    }
    __syncthreads();
    // single staging pass: filter to this sub, compute w, direct-scatter
    for (int e = tid; e < rcnt; e += 256) {
        uint32_t p = reg[e];
        int dstl = (int)(p >> 24);
        if ((dstl >> 5) == sub) {
            int n = dstl & 31;
            int src = (int)(p & 0xFFFFFFu);
            float sc = s_si[n] + s_j[src];
            sc = (sc > 0.f) ? sc : SLOPE * sc;
            float w = __expf(sc);
            int slot = atomicAdd(&lcur[n], 1);
            if (slot < NCAP)
                spairs[n * NCAP + slot] =
                    ((uint64_t)__float_as_uint(w) << 32) | (uint32_t)src;
        }
    }
    __syncthreads();
    int wave = tid >> 6, lane = tid & 63;
    int quarter = lane >> 4, ql = lane & 15;
    for (int k = wave; k < 32; k += 4) {
        int node = node0 + k;
        if (node >= N_NODES) break;
        float acc[4] = {0.f, 0.f, 0.f, 0.f};
        float den = 0.f;
        int c = lcur[k];
        if (c <= NCAP) {
            const uint64_t* pp = spairs + k * NCAP;
            int i = 0;
            for (; i + 16 <= c; i += 16) gat_batch4<4>(pp, i, quarter, ql, xw2, acc, den);
            if (i + 8 <= c) { gat_batch4<2>(pp, i, quarter, ql, xw2, acc, den); i += 8; }
            if (i + 4 <= c) { gat_batch4<1>(pp, i, quarter, ql, xw2, acc, den); i += 4; }
            int rem = c - i;
            if (rem > 0) {
                // masked final batch: inactive quarters load a valid row, w=0
                uint64_t q = pp[i + min(quarter, rem - 1)];
                float w = (quarter < rem) ? __uint_as_float((uint32_t)(q >> 32)) : 0.f;
                uint2 d = xw2[((uint32_t)q & 0xFFFFFFu) * 16 + ql];
                den += w;
                acc[0] = fmaf(w, bflo(d.x), acc[0]);
                acc[1] = fmaf(w, bfhi(d.x), acc[1]);
                acc[2] = fmaf(w, bflo(d.y), acc[2]);
                acc[3] = fmaf(w, bfhi(d.y), acc[3]);
            }
        } else {
            // per-node overflow fallback (P ~ 3e-10/node): direct region scan;
            // quarter 0 applies the weight, other quarters contribute 0
            int sn = (sub << 5) | k;
            for (int e = 0; e < rcnt; ++e) {
                uint32_t p = reg[e];
                if ((int)(p >> 24) == sn) {
                    int src = (int)(p & 0xFFFFFFu);
                    float sc = s_si[k] + s_j[src];
                    sc = (sc > 0.f) ? sc : SLOPE * sc;
                    float w = (quarter == 0) ? __expf(sc) : 0.f;
                    uint2 d = xw2[(uint32_t)src * 16 + ql];
                    den += w;
                    acc[0] = fmaf(w, bflo(d.x), acc[0]);
                    acc[1] = fmaf(w, bfhi(d.x), acc[1]);
                    acc[2] = fmaf(w, bflo(d.y), acc[2]);
                    acc[3] = fmaf(w, bfhi(d.y), acc[3]);
                }
            }
        }
        // combine the 4 quarters; lanes 0-15 then hold dims {4ql..4ql+3}
#pragma unroll
        for (int j = 0; j < 4; ++j) {
            acc[j] += __shfl_xor(acc[j], 16, 64);
            acc[j] += __shfl_xor(acc[j], 32, 64);
        }
        den += __shfl_xor(den, 16, 64);
        den += __shfl_xor(den, 32, 64);
        if (quarter == 0) {
            float4 r = make_float4(0.f, 0.f, 0.f, 0.f);
            if (c > 0) {
                float inv = 1.f / den;
                r.x = fmaxf(acc[0] * inv, 0.f);
                r.y = fmaxf(acc[1] * inv, 0.f);
                r.z = fmaxf(acc[2] * inv, 0.f);
                r.w = fmaxf(acc[3] * inv, 0.f);
            }
            ((float4*)(out + (size_t)node * HIDDEN))[ql] = r;
        }
    }
}

extern "C" void kernel_launch(void* const* d_in, const int* in_sizes, int n_in,
                              void* d_out, int out_size, void* d_ws, size_t ws_size,
                              hipStream_t stream) {
    const float* x   = (const float*)d_in[0];
    const int*   ei  = (const int*)d_in[1];   // [2, E]: row0 = src (ej), row1 = dst (ei)
    const float* w_i = (const float*)d_in[2];
    const float* w_j = (const float*)d_in[3];
    float* out = (float*)d_out;

    char* p = (char*)d_ws;
    float*          s_i    = (float*)p;          p += (size_t)N_NODES * 4;
    float*          s_j    = (float*)p;          p += (size_t)N_NODES * 4;
    unsigned short* xb     = (unsigned short*)p; p += (size_t)N_NODES * HIDDEN * 2;
    int*            cursor = (int*)p;            p += 4096;
    uint32_t*       pairs  = (uint32_t*)p;       // NBUCK * CAPB * 4 B = 8.8 MB

    const int* srcs = ei;             // edge_index[0]
    const int* dsts = ei + N_EDGES;   // edge_index[1]

    hipMemsetAsync(cursor, 0, NBUCK * sizeof(int), stream);
    k_build     <<<NPART + NSB, 256, 0, stream>>>(x, w_i, w_j, srcs, dsts,
                                                  s_i, s_j, xb, cursor, pairs);
    k_bucket_agg<<<(N_NODES + 31) / 32, 256, 0, stream>>>((const uint2*)xb, pairs, cursor,
                                                          s_i, s_j, out);
}